// Round 1
// baseline (257.547 us; speedup 1.0000x reference)
//
#include <hip/hip_runtime.h>
#include <hip/hip_bf16.h>
#include <math.h>

#define NB 4096   // batch
#define ND 2048   // feature dim
#define BM 128
#define BN 128
#define BKS 64    // K staged per LDS round

typedef __attribute__((ext_vector_type(8))) short short8;
typedef __attribute__((ext_vector_type(4))) float floatx4;

#define GLOAD_LDS16(g, l) \
  __builtin_amdgcn_global_load_lds((const __attribute__((address_space(1))) void*)(g), \
                                   (__attribute__((address_space(3))) void*)(l), 16, 0, 0)

// order-preserving float<->uint encode (min/max via unsigned atomics)
__device__ __forceinline__ unsigned fenc(float f) {
  unsigned u = __float_as_uint(f);
  return (u >> 31) ? ~u : (u | 0x80000000u);
}
__device__ __forceinline__ float fdec(unsigned u) {
  unsigned b = (u & 0x80000000u) ? (u ^ 0x80000000u) : ~u;
  return __uint_as_float(b);
}

__device__ __forceinline__ unsigned f2bf(float x) {  // RNE fp32 -> bf16 bits
  unsigned u = __float_as_uint(x);
  return (u + 0x7FFFu + ((u >> 16) & 1u)) >> 16;
}

// ---- kernel 1: L2-normalize rows, write bf16 matrix into ws ----
__global__ __launch_bounds__(256) void norm_kernel(const float* __restrict__ feats,
                                                   unsigned short* __restrict__ fb) {
  int row = blockIdx.x;
  int t = threadIdx.x;
  const float4* src = (const float4*)(feats + (size_t)row * ND);
  float4 v0 = src[t * 2];
  float4 v1 = src[t * 2 + 1];
  float ss = v0.x * v0.x + v0.y * v0.y + v0.z * v0.z + v0.w * v0.w +
             v1.x * v1.x + v1.y * v1.y + v1.z * v1.z + v1.w * v1.w;
  for (int off = 32; off > 0; off >>= 1) ss += __shfl_down(ss, off);
  __shared__ float wsum[4];
  int lane = t & 63, wid = t >> 6;
  if (lane == 0) wsum[wid] = ss;
  __syncthreads();
  float tot = wsum[0] + wsum[1] + wsum[2] + wsum[3];
  float inv = 1.0f / (sqrtf(tot) + 1e-12f);
  float a0 = v0.x * inv, a1 = v0.y * inv, a2 = v0.z * inv, a3 = v0.w * inv;
  float a4 = v1.x * inv, a5 = v1.y * inv, a6 = v1.z * inv, a7 = v1.w * inv;
  uint4 o;
  o.x = f2bf(a0) | (f2bf(a1) << 16);
  o.y = f2bf(a2) | (f2bf(a3) << 16);
  o.z = f2bf(a4) | (f2bf(a5) << 16);
  o.w = f2bf(a6) | (f2bf(a7) << 16);
  ((uint4*)(fb + (size_t)row * ND))[t] = o;
}

// ---- kernel 2: init row stats ----
__global__ void init_kernel(unsigned* gpm, unsigned* gnm, float* gps, float* gns) {
  int i = blockIdx.x * blockDim.x + threadIdx.x;
  if (i < NB) {
    gpm[i] = 0xFFFFFFFFu;  // +inf-ish sentinel (decodes NaN -> comparisons false, matches ref empty-min)
    gnm[i] = 0u;           // -inf-ish sentinel
    gps[i] = 0.f;
    gns[i] = 0.f;
  }
}

// ---- kernels 3/4: tiled bf16 MFMA sim-matrix pass with fused epilogue ----
// PASS 0: per-row pos_min / neg_max.  PASS 1: masked exp sums.
template <int PASS>
__global__ __launch_bounds__(256) void pass_kernel(const unsigned short* __restrict__ fb,
                                                   const int* __restrict__ labels,
                                                   unsigned* __restrict__ gpm,
                                                   unsigned* __restrict__ gnm,
                                                   float* __restrict__ gps,
                                                   float* __restrict__ gns) {
  __shared__ unsigned short As[BM * BKS];
  __shared__ unsigned short Bs[BN * BKS];
  __shared__ int rowlab[BM], collab[BN];
  __shared__ unsigned pmE[BM], nmE[BM];   // pass 0
  __shared__ float fps[BM], fns[BM];      // pass 1 sums
  __shared__ float rpm[BM], rnm[BM];      // pass 1 thresholds

  int t = threadIdx.x;
  int l = t & 63, w = t >> 6;
  int wr = w >> 1, wc = w & 1;
  int row0 = blockIdx.x * BM, col0 = blockIdx.y * BN;

  if (t < BM) {
    rowlab[t] = labels[row0 + t];
    collab[t] = labels[col0 + t];
    if (PASS == 0) {
      pmE[t] = 0xFFFFFFFFu;
      nmE[t] = 0u;
    } else {
      fps[t] = 0.f;
      fns[t] = 0.f;
      rpm[t] = fdec(gpm[row0 + t]);
      rnm[t] = fdec(gnm[row0 + t]);
    }
  }

  floatx4 acc[4][4];
#pragma unroll
  for (int m = 0; m < 4; m++)
#pragma unroll
    for (int n = 0; n < 4; n++) acc[m][n] = (floatx4){0.f, 0.f, 0.f, 0.f};

  // staging geometry: per issue q, wave w covers rows q*32 + w*8 + (l>>3), 16B chunk (l&7)
  int srow = w * 8 + (l >> 3);
  int scol = (l & 7) * 8;  // element offset within K window

  for (int kt = 0; kt < ND; kt += BKS) {
    __syncthreads();  // previous tile's ds_reads done before overwrite
#pragma unroll
    for (int q = 0; q < 4; q++) {
      int r = q * 32 + srow;
      GLOAD_LDS16(fb + (size_t)(row0 + r) * ND + kt + scol, (char*)As + (q * 32 + w * 8) * 128);
      GLOAD_LDS16(fb + (size_t)(col0 + r) * ND + kt + scol, (char*)Bs + (q * 32 + w * 8) * 128);
    }
    __syncthreads();  // drains vmcnt (global_load_lds) before consuming
#pragma unroll
    for (int s = 0; s < 2; s++) {
      short8 a[4], b[4];
#pragma unroll
      for (int m = 0; m < 4; m++)
        a[m] = *(const short8*)(As + (wr * 64 + m * 16 + (l & 15)) * BKS + s * 32 + (l >> 4) * 8);
#pragma unroll
      for (int n = 0; n < 4; n++)
        b[n] = *(const short8*)(Bs + (wc * 64 + n * 16 + (l & 15)) * BKS + s * 32 + (l >> 4) * 8);
#pragma unroll
      for (int m = 0; m < 4; m++)
#pragma unroll
        for (int n = 0; n < 4; n++)
          acc[m][n] = __builtin_amdgcn_mfma_f32_16x16x32_bf16(a[m], b[n], acc[m][n], 0, 0, 0);
    }
  }

  // epilogue: C/D layout col = lane&15, row = (lane>>4)*4 + reg (m89-verified)
#pragma unroll
  for (int m = 0; m < 4; m++) {
#pragma unroll
    for (int v = 0; v < 4; v++) {
      int row_l = wr * 64 + m * 16 + (l >> 4) * 4 + v;
      int rl = rowlab[row_l];
      int grow = row0 + row_l;
      if (PASS == 0) {
        float pmin = 3.0e38f, nmax = -3.0e38f;
        bool anyp = false, anyn = false;
#pragma unroll
        for (int n = 0; n < 4; n++) {
          int col_l = wc * 64 + n * 16 + (l & 15);
          float s = acc[m][n][v];
          if (rl == collab[col_l]) {
            if ((col0 + col_l) != grow && s < 0.99999f) { pmin = fminf(pmin, s); anyp = true; }
          } else {
            nmax = fmaxf(nmax, s);
            anyn = true;
          }
        }
        if (anyp) atomicMin(&pmE[row_l], fenc(pmin));
        if (anyn) atomicMax(&nmE[row_l], fenc(nmax));
      } else {
        float pm = rpm[row_l], nm = rnm[row_l];
        float ps = 0.f, ns = 0.f;
#pragma unroll
        for (int n = 0; n < 4; n++) {
          int col_l = wc * 64 + n * 16 + (l & 15);
          float s = acc[m][n][v];
          if (rl == collab[col_l]) {
            if ((col0 + col_l) != grow && s < 0.99999f && (s - 0.1f < nm))
              ps += __expf(-2.0f * (s - 0.5f));
          } else {
            if (s + 0.1f > pm) ns += __expf(40.0f * (s - 0.5f));
          }
        }
        if (ps != 0.f) atomicAdd(&fps[row_l], ps);
        if (ns != 0.f) atomicAdd(&fns[row_l], ns);
      }
    }
  }
  __syncthreads();
  if (t < BM) {
    if (PASS == 0) {
      if (pmE[t] != 0xFFFFFFFFu) atomicMin(&gpm[row0 + t], pmE[t]);
      if (nmE[t] != 0u) atomicMax(&gnm[row0 + t], nmE[t]);
    } else {
      if (fps[t] != 0.f) atomicAdd(&gps[row0 + t], fps[t]);
      if (fns[t] != 0.f) atomicAdd(&gns[row0 + t], fns[t]);
    }
  }
}

// ---- kernel 5: finalize scalar loss ----
__global__ __launch_bounds__(256) void finalize_kernel(const float* __restrict__ gps,
                                                       const float* __restrict__ gns,
                                                       float* __restrict__ out) {
  int t = threadIdx.x;
  float sum = 0.f;
  for (int i = t; i < NB; i += 256) {
    float ps = gps[i], ns = gns[i];
    if (ps > 0.f && ns > 0.f) sum += 0.5f * log1pf(ps) + 0.025f * log1pf(ns);
  }
  for (int off = 32; off > 0; off >>= 1) sum += __shfl_down(sum, off);
  __shared__ float wsum[4];
  int lane = t & 63, wid = t >> 6;
  if (lane == 0) wsum[wid] = sum;
  __syncthreads();
  if (t == 0) out[0] = (wsum[0] + wsum[1] + wsum[2] + wsum[3]) / (float)NB;
}

extern "C" void kernel_launch(void* const* d_in, const int* in_sizes, int n_in,
                              void* d_out, int out_size, void* d_ws, size_t ws_size,
                              hipStream_t stream) {
  const float* feats = (const float*)d_in[0];
  const int* labels = (const int*)d_in[1];

  char* ws = (char*)d_ws;
  unsigned short* fb = (unsigned short*)ws;            // 4096*2048*2 = 16 MB
  size_t off = (size_t)NB * ND * 2;
  unsigned* gpm = (unsigned*)(ws + off); off += NB * 4;
  unsigned* gnm = (unsigned*)(ws + off); off += NB * 4;
  float* gps = (float*)(ws + off); off += NB * 4;
  float* gns = (float*)(ws + off); off += NB * 4;

  norm_kernel<<<NB, 256, 0, stream>>>(feats, fb);
  init_kernel<<<NB / 256, 256, 0, stream>>>(gpm, gnm, gps, gns);
  dim3 grid(NB / BM, NB / BN);
  pass_kernel<0><<<grid, 256, 0, stream>>>(fb, labels, gpm, gnm, gps, gns);
  pass_kernel<1><<<grid, 256, 0, stream>>>(fb, labels, gpm, gnm, gps, gns);
  finalize_kernel<<<1, 256, 0, stream>>>(gps, gns, (float*)d_out);
}

// Round 2
// 145.921 us; speedup vs baseline: 1.7650x; 1.7650x over previous
//
#include <hip/hip_runtime.h>
#include <hip/hip_bf16.h>
#include <math.h>

#define NB 4096   // batch
#define ND 2048   // feature dim
#define BM 128
#define BKS 64    // K staged per LDS round
#define NTB (NB / BM)   // 32 tile-blocks per dim
#define TPAD 136        // padded fp16 tile row (272 B: 16B-aligned, mild col-read conflicts)

typedef __attribute__((ext_vector_type(8))) short short8;
typedef __attribute__((ext_vector_type(4))) float floatx4;

#define GLOAD_LDS16(g, l) \
  __builtin_amdgcn_global_load_lds((const __attribute__((address_space(1))) void*)(g), \
                                   (__attribute__((address_space(3))) void*)(l), 16, 0, 0)

// order-preserving float<->uint encode (min/max via unsigned atomics)
__device__ __forceinline__ unsigned fenc(float f) {
  unsigned u = __float_as_uint(f);
  return (u >> 31) ? ~u : (u | 0x80000000u);
}
__device__ __forceinline__ float fdec(unsigned u) {
  unsigned b = (u & 0x80000000u) ? (u ^ 0x80000000u) : ~u;
  return __uint_as_float(b);
}

__device__ __forceinline__ unsigned f2bf(float x) {  // RNE fp32 -> bf16 bits
  unsigned u = __float_as_uint(x);
  return (u + 0x7FFFu + ((u >> 16) & 1u)) >> 16;
}

union H16 { unsigned short u; _Float16 h; };
__device__ __forceinline__ unsigned short f2h(float x) { H16 c; c.h = (_Float16)x; return c.u; }
__device__ __forceinline__ float h2f(unsigned short u) { H16 c; c.u = u; return (float)c.h; }

// ---- kernel 1: L2-normalize rows, write bf16 matrix into ws ----
__global__ __launch_bounds__(256) void norm_kernel(const float* __restrict__ feats,
                                                   unsigned short* __restrict__ fb) {
  int row = blockIdx.x;
  int t = threadIdx.x;
  const float4* src = (const float4*)(feats + (size_t)row * ND);
  float4 v0 = src[t * 2];
  float4 v1 = src[t * 2 + 1];
  float ss = v0.x * v0.x + v0.y * v0.y + v0.z * v0.z + v0.w * v0.w +
             v1.x * v1.x + v1.y * v1.y + v1.z * v1.z + v1.w * v1.w;
  for (int off = 32; off > 0; off >>= 1) ss += __shfl_down(ss, off);
  __shared__ float wsum[4];
  int lane = t & 63, wid = t >> 6;
  if (lane == 0) wsum[wid] = ss;
  __syncthreads();
  float tot = wsum[0] + wsum[1] + wsum[2] + wsum[3];
  float inv = 1.0f / (sqrtf(tot) + 1e-12f);
  float a0 = v0.x * inv, a1 = v0.y * inv, a2 = v0.z * inv, a3 = v0.w * inv;
  float a4 = v1.x * inv, a5 = v1.y * inv, a6 = v1.z * inv, a7 = v1.w * inv;
  uint4 o;
  o.x = f2bf(a0) | (f2bf(a1) << 16);
  o.y = f2bf(a2) | (f2bf(a3) << 16);
  o.z = f2bf(a4) | (f2bf(a5) << 16);
  o.w = f2bf(a6) | (f2bf(a7) << 16);
  ((uint4*)(fb + (size_t)row * ND))[t] = o;
}

// ---- kernel 2: init row stats ----
__global__ void init_kernel(unsigned* gpm, unsigned* gnm) {
  int i = blockIdx.x * blockDim.x + threadIdx.x;
  if (i < NB) {
    gpm[i] = 0xFFFFFFFFu;  // decodes to NaN -> comparisons false (empty-min semantics)
    gnm[i] = 0u;           // decodes to NaN
  }
}

// ---- kernel 3: symmetric GEMM over upper-tri tile blocks ----
// Computes row min/max stats for BOTH tile rows and tile cols, and stores the
// fp16 sim tile (plus transposed mirror for off-diagonal blocks).
__global__ __launch_bounds__(256) void pass0_kernel(const unsigned short* __restrict__ fb,
                                                    const int* __restrict__ labels,
                                                    unsigned* __restrict__ gpm,
                                                    unsigned* __restrict__ gnm,
                                                    unsigned short* __restrict__ sim) {
  __shared__ __align__(16) char shraw[TPAD * BM * 2];  // union: {As,Bs} then fp16 tile
  unsigned short* As = (unsigned short*)shraw;
  unsigned short* Bs = (unsigned short*)(shraw + BM * BKS * 2);
  __shared__ int rowlab[BM], collab[BM];
  __shared__ unsigned pmR[BM], nmR[BM], pmC[BM], nmC[BM];

  int t = threadIdx.x;
  int l = t & 63, w = t >> 6;
  int wr = w >> 1, wc = w & 1;

  // decode upper-triangular block index: row bi has (NTB - bi) blocks
  int rem = blockIdx.x, bi = 0;
  while (rem >= NTB - bi) { rem -= NTB - bi; bi++; }
  int bj = bi + rem;
  int row0 = bi * BM, col0 = bj * BM;

  if (t < BM) {
    rowlab[t] = labels[row0 + t];
    collab[t] = labels[col0 + t];
    pmR[t] = 0xFFFFFFFFu; nmR[t] = 0u;
    pmC[t] = 0xFFFFFFFFu; nmC[t] = 0u;
  }

  floatx4 acc[4][4];
#pragma unroll
  for (int m = 0; m < 4; m++)
#pragma unroll
    for (int n = 0; n < 4; n++) acc[m][n] = (floatx4){0.f, 0.f, 0.f, 0.f};

  int srow = w * 8 + (l >> 3);
  int scol = (l & 7) * 8;

  for (int kt = 0; kt < ND; kt += BKS) {
    __syncthreads();
#pragma unroll
    for (int q = 0; q < 4; q++) {
      int r = q * 32 + srow;
      GLOAD_LDS16(fb + (size_t)(row0 + r) * ND + kt + scol, (char*)As + (q * 32 + w * 8) * 128);
      GLOAD_LDS16(fb + (size_t)(col0 + r) * ND + kt + scol, (char*)Bs + (q * 32 + w * 8) * 128);
    }
    __syncthreads();
#pragma unroll
    for (int s = 0; s < 2; s++) {
      short8 a[4], b[4];
#pragma unroll
      for (int m = 0; m < 4; m++)
        a[m] = *(const short8*)(As + (wr * 64 + m * 16 + (l & 15)) * BKS + s * 32 + (l >> 4) * 8);
#pragma unroll
      for (int n = 0; n < 4; n++)
        b[n] = *(const short8*)(Bs + (wc * 64 + n * 16 + (l & 15)) * BKS + s * 32 + (l >> 4) * 8);
#pragma unroll
      for (int m = 0; m < 4; m++)
#pragma unroll
        for (int n = 0; n < 4; n++)
          acc[m][n] = __builtin_amdgcn_mfma_f32_16x16x32_bf16(a[m], b[n], acc[m][n], 0, 0, 0);
    }
  }

  // ---- stats from registers (C/D layout: col = lane&15, row = (lane>>4)*4 + reg) ----
  // row-attributed stats
#pragma unroll
  for (int m = 0; m < 4; m++) {
#pragma unroll
    for (int v = 0; v < 4; v++) {
      int row_l = wr * 64 + m * 16 + (l >> 4) * 4 + v;
      int rl = rowlab[row_l];
      int grow = row0 + row_l;
      float pmin = 3.0e38f, nmax = -3.0e38f;
      bool anyp = false, anyn = false;
#pragma unroll
      for (int n = 0; n < 4; n++) {
        int col_l = wc * 64 + n * 16 + (l & 15);
        float s = acc[m][n][v];
        if (rl == collab[col_l]) {
          if ((col0 + col_l) != grow && s < 0.99999f) { pmin = fminf(pmin, s); anyp = true; }
        } else {
          nmax = fmaxf(nmax, s);
          anyn = true;
        }
      }
      if (anyp) atomicMin(&pmR[row_l], fenc(pmin));
      if (anyn) atomicMax(&nmR[row_l], fenc(nmax));
    }
  }
  // col-attributed stats (mirror rows); idempotent duplicate on diagonal blocks
#pragma unroll
  for (int n = 0; n < 4; n++) {
    int col_l = wc * 64 + n * 16 + (l & 15);
    int cl = collab[col_l];
    int gcol = col0 + col_l;
    float pmin = 3.0e38f, nmax = -3.0e38f;
    bool anyp = false, anyn = false;
#pragma unroll
    for (int m = 0; m < 4; m++) {
#pragma unroll
      for (int v = 0; v < 4; v++) {
        int row_l = wr * 64 + m * 16 + (l >> 4) * 4 + v;
        float s = acc[m][n][v];
        if (rowlab[row_l] == cl) {
          if ((row0 + row_l) != gcol && s < 0.99999f) { pmin = fminf(pmin, s); anyp = true; }
        } else {
          nmax = fmaxf(nmax, s);
          anyn = true;
        }
      }
    }
    if (anyp) atomicMin(&pmC[col_l], fenc(pmin));
    if (anyn) atomicMax(&nmC[col_l], fenc(nmax));
  }

  __syncthreads();  // all waves done reading As/Bs + stats atomics visible

  // ---- write fp16 tile into LDS (overwrites As/Bs) ----
  unsigned short (*tile)[TPAD] = (unsigned short(*)[TPAD])shraw;
#pragma unroll
  for (int m = 0; m < 4; m++)
#pragma unroll
    for (int v = 0; v < 4; v++) {
      int row_l = wr * 64 + m * 16 + (l >> 4) * 4 + v;
#pragma unroll
      for (int n = 0; n < 4; n++) {
        int col_l = wc * 64 + n * 16 + (l & 15);
        tile[row_l][col_l] = f2h(acc[m][n][v]);
      }
    }
  __syncthreads();

  // ---- direct store: coalesced rows ----
  {
    int r = t >> 1, h = t & 1;
    const unsigned short* src = &tile[r][h * 64];
    unsigned short* dst = sim + (size_t)(row0 + r) * NB + col0 + h * 64;
#pragma unroll
    for (int k = 0; k < 8; k++)
      *(short8*)(dst + k * 8) = *(const short8*)(src + k * 8);
  }
  // ---- mirror store (transposed) for off-diagonal blocks ----
  if (bi != bj) {
    int mc = t >> 1, h = t & 1;
    short8 buf[8];
#pragma unroll
    for (int k = 0; k < 64; k++)
      buf[k / 8][k % 8] = (short)tile[h * 64 + k][mc];
    unsigned short* dst = sim + (size_t)(col0 + mc) * NB + row0 + h * 64;
#pragma unroll
    for (int k = 0; k < 8; k++)
      *(short8*)(dst + k * 8) = buf[k];
  }

  // ---- merge stats to global ----
  if (t < BM) {
    if (pmR[t] != 0xFFFFFFFFu) atomicMin(&gpm[row0 + t], pmR[t]);
    if (nmR[t] != 0u) atomicMax(&gnm[row0 + t], nmR[t]);
    if (pmC[t] != 0xFFFFFFFFu) atomicMin(&gpm[col0 + t], pmC[t]);
    if (nmC[t] != 0u) atomicMax(&gnm[col0 + t], nmC[t]);
  }
}

// ---- kernel 4: streaming masked exp-sums, one wave per row ----
__global__ __launch_bounds__(256) void sums_kernel(const unsigned short* __restrict__ sim,
                                                   const int* __restrict__ labels,
                                                   const unsigned* __restrict__ gpm,
                                                   const unsigned* __restrict__ gnm,
                                                   float* __restrict__ gps,
                                                   float* __restrict__ gns) {
  int t = threadIdx.x, l = t & 63, w = t >> 6;
  int r = blockIdx.x * 4 + w;
  int rl = labels[r];
  float pm = fdec(gpm[r]);  // pos_min (NaN if none -> masks false)
  float nm = fdec(gnm[r]);  // neg_max
  const unsigned short* row = sim + (size_t)r * NB;
  float ps = 0.f, ns = 0.f;
#pragma unroll
  for (int it = 0; it < 8; it++) {
    int j0 = it * 512 + l * 8;
    short8 sv = *(const short8*)(row + j0);
    int4 lb0 = *(const int4*)(labels + j0);
    int4 lb1 = *(const int4*)(labels + j0 + 4);
    int lb[8] = {lb0.x, lb0.y, lb0.z, lb0.w, lb1.x, lb1.y, lb1.z, lb1.w};
#pragma unroll
    for (int e = 0; e < 8; e++) {
      float s = h2f((unsigned short)sv[e]);
      int j = j0 + e;
      if (lb[e] == rl) {
        if (j != r && s < 0.99999f && (s - 0.1f < nm)) ps += __expf(-2.0f * (s - 0.5f));
      } else {
        if (s + 0.1f > pm) ns += __expf(40.0f * (s - 0.5f));
      }
    }
  }
  for (int off = 32; off > 0; off >>= 1) {
    ps += __shfl_down(ps, off);
    ns += __shfl_down(ns, off);
  }
  if (l == 0) { gps[r] = ps; gns[r] = ns; }
}

// ---- kernel 5: finalize scalar loss ----
__global__ __launch_bounds__(256) void finalize_kernel(const float* __restrict__ gps,
                                                       const float* __restrict__ gns,
                                                       float* __restrict__ out) {
  int t = threadIdx.x;
  float sum = 0.f;
  for (int i = t; i < NB; i += 256) {
    float ps = gps[i], ns = gns[i];
    if (ps > 0.f && ns > 0.f) sum += 0.5f * log1pf(ps) + 0.025f * log1pf(ns);
  }
  for (int off = 32; off > 0; off >>= 1) sum += __shfl_down(sum, off);
  __shared__ float wsum[4];
  int lane = t & 63, wid = t >> 6;
  if (lane == 0) wsum[wid] = sum;
  __syncthreads();
  if (t == 0) out[0] = (wsum[0] + wsum[1] + wsum[2] + wsum[3]) / (float)NB;
}

extern "C" void kernel_launch(void* const* d_in, const int* in_sizes, int n_in,
                              void* d_out, int out_size, void* d_ws, size_t ws_size,
                              hipStream_t stream) {
  const float* feats = (const float*)d_in[0];
  const int* labels = (const int*)d_in[1];

  char* ws = (char*)d_ws;
  unsigned short* fb = (unsigned short*)ws;                  // 16 MB bf16 normalized feats
  size_t off = (size_t)NB * ND * 2;
  unsigned short* sim = (unsigned short*)(ws + off);         // 32 MB fp16 sim matrix
  off += (size_t)NB * NB * 2;
  unsigned* gpm = (unsigned*)(ws + off); off += NB * 4;
  unsigned* gnm = (unsigned*)(ws + off); off += NB * 4;
  float* gps = (float*)(ws + off); off += NB * 4;
  float* gns = (float*)(ws + off); off += NB * 4;

  norm_kernel<<<NB, 256, 0, stream>>>(feats, fb);
  init_kernel<<<NB / 256, 256, 0, stream>>>(gpm, gnm);
  int nblk = NTB * (NTB + 1) / 2;  // 528 upper-tri blocks
  pass0_kernel<<<nblk, 256, 0, stream>>>(fb, labels, gpm, gnm, sim);
  sums_kernel<<<NB / 4, 256, 0, stream>>>(sim, labels, gpm, gnm, gps, gns);
  finalize_kernel<<<1, 256, 0, stream>>>(gps, gns, (float*)d_out);
}